// Round 16
// baseline (65.247 us; speedup 1.0000x reference)
//
#include <hip/hip_runtime.h>
#include <hip/hip_bf16.h>
#include <math.h>

typedef __attribute__((ext_vector_type(8))) _Float16 half8;
typedef __attribute__((ext_vector_type(2))) _Float16 half2v;
typedef __attribute__((ext_vector_type(4))) float f32x4;
typedef __attribute__((ext_vector_type(4))) unsigned int u32x4;

#define NPT 1024
#define D   128

__device__ __forceinline__ unsigned int absdiff_pk(unsigned int a, unsigned int b) {
  half2v d = __builtin_bit_cast(half2v, a) - __builtin_bit_cast(half2v, b);
  return __builtin_bit_cast(unsigned int, d) & 0x7FFF7FFFu;
}
__device__ __forceinline__ unsigned int pk_max(unsigned int a, unsigned int b) {
  unsigned int r;
  asm("v_pk_max_f16 %0, %1, %2" : "=v"(r) : "v"(a), "v"(b));
  return r;
}
__device__ __forceinline__ unsigned int pkrtz(float lo, float hi) {
  return __builtin_bit_cast(unsigned int, __builtin_amdgcn_cvt_pkrtz(lo, hi));
}
__device__ __forceinline__ float fdot2(unsigned int a, unsigned int b, float c) {
  return __builtin_amdgcn_fdot2(__builtin_bit_cast(half2v, a),
                                __builtin_bit_cast(half2v, b), c, false);
}

// ---------------- kernel 1: prep ----------------
// xsw: swizzled f16 x: row i base i*256B, elem k at ((2k)^((i&7)<<4))
// w1p: fragment-ordered f16 W1: w1p[((k>>3)*128+hid)*8 + (k&7)] = W1[k][hid]
// xwghT: f16 [128 t][1024 i] transpose of x@Wg
__global__ __launch_bounds__(128) void k_prep(const float* __restrict__ x,
                                              const float* __restrict__ W1,
                                              const float* __restrict__ Wg,
                                              float* __restrict__ deg,
                                              unsigned short* __restrict__ xsw,
                                              unsigned short* __restrict__ w1p,
                                              unsigned short* __restrict__ xwghT) {
  __shared__ float xi[D];
  const int i = blockIdx.x;
  const int t = threadIdx.x;
  const float xv = x[i * D + t];
  xi[t] = xv;
  if (t == 0) deg[i] = 0.f;
  const _Float16 hv = (_Float16)xv;
  const int byte = i * 256 + ((2 * t) ^ ((i & 7) << 4));
  *(unsigned short*)((unsigned char*)xsw + byte) =
      __builtin_bit_cast(unsigned short, hv);
  if (i < 128) {  // t = k, i = hid
    const _Float16 wv = (_Float16)W1[t * 128 + i];
    w1p[((t >> 3) * 128 + i) * 8 + (t & 7)] = __builtin_bit_cast(unsigned short, wv);
  }
  __syncthreads();
  float a0 = 0.f, a1 = 0.f, a2 = 0.f, a3 = 0.f;
#pragma unroll 8
  for (int k = 0; k < D; k += 4) {
    a0 += xi[k + 0] * Wg[(k + 0) * D + t];
    a1 += xi[k + 1] * Wg[(k + 1) * D + t];
    a2 += xi[k + 2] * Wg[(k + 2) * D + t];
    a3 += xi[k + 3] * Wg[(k + 3) * D + t];
  }
  const _Float16 av = (_Float16)((a0 + a1) + (a2 + a3));
  xwghT[t * NPT + i] = __builtin_bit_cast(unsigned short, av);
}

// phase: absdiff + 32 MFMA for the group currently in jr -> acc
__device__ __forceinline__ void phase_mfma(f32x4 (&acc)[8], const u32x4 (&jr)[4],
                                           const u32x4 (&xiu)[4],
                                           const half8 (&w1f)[4][8]) {
#pragma unroll
  for (int ht = 0; ht < 8; ++ht) acc[ht] = f32x4{0.f, 0.f, 0.f, 0.f};
  __builtin_amdgcn_s_setprio(1);
#pragma unroll
  for (int ks = 0; ks < 4; ++ks) {
    u32x4 afu;
#pragma unroll
    for (int p4 = 0; p4 < 4; ++p4) afu[p4] = absdiff_pk(jr[ks][p4], xiu[ks][p4]);
    const half8 af = __builtin_bit_cast(half8, afu);
#pragma unroll
    for (int ht = 0; ht < 8; ++ht)
      acc[ht] = __builtin_amdgcn_mfma_f32_16x16x32_f16(w1f[ks][ht], af, acc[ht], 0, 0, 0);
  }
  __builtin_amdgcn_s_setprio(0);
}

__device__ __forceinline__ void reload(u32x4 (&jr)[4], const unsigned char* base,
                                       int kb0, int kb1, int kb2, int kb3) {
  jr[0] = *(const u32x4*)(base + kb0);
  jr[1] = *(const u32x4*)(base + kb1);
  jr[2] = *(const u32x4*)(base + kb2);
  jr[3] = *(const u32x4*)(base + kb3);
}

// dot of a completed acc (constants from per-wave LDS table) -> sbuf
__device__ __forceinline__ void dot_store(const f32x4 (&acc)[8], const u32x4* cstw,
                                          float* sbw, int grp, int lane, int l15,
                                          int g) {
  float s0 = 0.f, s1 = 0.f, s2 = 0.f, s3 = 0.f;
#pragma unroll
  for (int ht = 0; ht < 8; ht += 2) {
    const u32x4 cA = cstw[ht * 4 + g];
    const u32x4 cB = cstw[(ht + 1) * 4 + g];
    unsigned int h0a = pk_max(pkrtz(acc[ht][0], acc[ht][1]), cA[0]);
    unsigned int h0b = pk_max(pkrtz(acc[ht][2], acc[ht][3]), cA[1]);
    unsigned int h1a = pk_max(pkrtz(acc[ht + 1][0], acc[ht + 1][1]), cB[0]);
    unsigned int h1b = pk_max(pkrtz(acc[ht + 1][2], acc[ht + 1][3]), cB[1]);
    s0 = fdot2(h0a, cA[2], s0);
    s1 = fdot2(h0b, cA[3], s1);
    s2 = fdot2(h1a, cB[2], s2);
    s3 = fdot2(h1b, cB[3], s3);
  }
  float s = (s0 + s1) + (s2 + s3);
  s += __shfl_xor(s, 16);
  s += __shfl_xor(s, 32);
  if (lane < 16) sbw[grp * 16 + l15] = s;
}

// ---------------- kernel 2: adjacency (2-deep pipelined: dot(q-1) under MFMA(q)) ----
// grid (256,2) x 256 thr. Wave = 1 i-row x 512 j (32 groups of 16, rotated order).
// W1 in 128 regs (AGPR side); dot constants in per-wave LDS; single jr bank;
// double acc bank; LDS-deferred sigmoid epilogue.
__global__ __launch_bounds__(256, 2) void k_adj(const unsigned short* __restrict__ xsw,
                                                const unsigned short* __restrict__ w1p,
                                                const float* __restrict__ b1,
                                                const float* __restrict__ W2,
                                                const float* __restrict__ b2,
                                                float* __restrict__ adj,
                                                float* __restrict__ deg) {
  __shared__ float sbuf[4][512];
  __shared__ u32x4 cst[4][32];  // [w][ht*4+g] = {nb1lo, nb1hi, w2lo, w2hi}

  const int tid  = threadIdx.x;
  const int lane = tid & 63;
  const int w    = tid >> 6;   // 0..3
  const int l15  = lane & 15;
  const int g    = lane >> 4;  // 0..3
  const int i  = blockIdx.x * 4 + w;
  const int jq = blockIdx.y;   // 0..1, 512 j each
  const int rot = ((w * 2 + jq) & 7) * 4;  // anti-phase co-resident waves

  // W1 -> regs: A[m=hid][k], hid = ht*16+l15, k = ks*32+g*8+e
  half8 w1f[4][8];
#pragma unroll
  for (int ks = 0; ks < 4; ++ks)
#pragma unroll
    for (int ht = 0; ht < 8; ++ht)
      w1f[ks][ht] = *(const half8*)(w1p + ((ks * 4 + g) * 128 + ht * 16 + l15) * 8);

  // relu(a+b1)*w2 = max(a,-b1)*w2 + b1*w2 ; constants -> per-wave LDS table
  float c0 = 0.f;
#pragma unroll
  for (int ht = 0; ht < 8; ++ht) {
    const f32x4 bv = *(const f32x4*)&b1[ht * 16 + g * 4];
    const f32x4 wv = *(const f32x4*)&W2[ht * 16 + g * 4];
    c0 += bv[0] * wv[0] + bv[1] * wv[1] + bv[2] * wv[2] + bv[3] * wv[3];
    if (l15 == 0) {
      u32x4 c;
      c[0] = pkrtz(-bv[0], -bv[1]);
      c[1] = pkrtz(-bv[2], -bv[3]);
      c[2] = pkrtz(wv[0], wv[1]);
      c[3] = pkrtz(wv[2], wv[3]);
      cst[w][ht * 4 + g] = c;
    }
  }
  c0 += __shfl_xor(c0, 16);
  c0 += __shfl_xor(c0, 32);
  const float B2 = b2[0] + c0;

  // xi fragments (broadcast row i)
  const unsigned char* xsb = (const unsigned char*)xsw;
  const unsigned char* xrow = xsb + i * 256;
  const int sxI = (i & 7) << 4;
  u32x4 xiu[4];
#pragma unroll
  for (int ks = 0; ks < 4; ++ks)
    xiu[ks] = *(const u32x4*)(xrow + ((ks * 64 + g * 16) ^ sxI));

  const int sxJ = (l15 & 7) << 4;
  const unsigned char* jrow = xsb + (jq * 512 + l15) * 256;
  const int kb0 = (0 * 64 + g * 16) ^ sxJ;
  const int kb1 = (1 * 64 + g * 16) ^ sxJ;
  const int kb2 = (2 * 64 + g * 16) ^ sxJ;
  const int kb3 = (3 * 64 + g * 16) ^ sxJ;

  __syncthreads();  // cst visible (paranoia; per-wave table)

  const u32x4* cstw = cst[w];
  float* sbw = sbuf[w];

  u32x4 jr[4];
  f32x4 accA[8], accB[8];

  reload(jr, jrow + rot * 4096, kb0, kb1, kb2, kb3);          // logical group 0
  phase_mfma(accA, jr, xiu, w1f);
  reload(jr, jrow + (((1 + rot) & 31) * 4096), kb0, kb1, kb2, kb3);

#pragma unroll 1
  for (int q = 1; q < 31; q += 2) {
    phase_mfma(accB, jr, xiu, w1f);                           // logical q
    reload(jr, jrow + (((q + 1 + rot) & 31) * 4096), kb0, kb1, kb2, kb3);
    dot_store(accA, cstw, sbw, (q - 1 + rot) & 31, lane, l15, g);
    phase_mfma(accA, jr, xiu, w1f);                           // logical q+1
    reload(jr, jrow + (((q + 2 + rot) & 31) * 4096), kb0, kb1, kb2, kb3);
    dot_store(accB, cstw, sbw, (q + rot) & 31, lane, l15, g);
  }
  phase_mfma(accB, jr, xiu, w1f);                             // logical 31
  dot_store(accA, cstw, sbw, (30 + rot) & 31, lane, l15, g);
  dot_store(accB, cstw, sbw, (31 + rot) & 31, lane, l15, g);

  // epilogue: all-lane sigmoid + coalesced stores + one deg atomic per wave
  float degacc = 0.f;
#pragma unroll
  for (int it = 0; it < 2; ++it) {
    const f32x4 sv = *(const f32x4*)&sbw[it * 256 + lane * 4];
    f32x4 ov;
#pragma unroll
    for (int e = 0; e < 4; ++e) {
      ov[e] = 1.f / (1.f + __expf(-(sv[e] + B2)));
      degacc += ov[e];
    }
    *(f32x4*)&adj[i * NPT + jq * 512 + it * 256 + lane * 4] = ov;
  }
#pragma unroll
  for (int m = 1; m < 64; m <<= 1) degacc += __shfl_xor(degacc, m);
  if (lane == 0) atomicAdd(&deg[i], degacc);
}

// ---------------- kernel 3: fused d1 (dinv-LDS prologue, MFMA, leaky epilogue) ----
// out[i][t] = leaky( dinv_i * sum_j xwghT[t][j]*(adj[i][j]*dinv_j) + bg[t] )
// grid 64 x 256 thr (4 waves). Block: 16 i x ALL 128 t. adj read exactly once.
__global__ __launch_bounds__(256) void k_d1(const float* __restrict__ adj,
                                            const unsigned short* __restrict__ xwghT,
                                            const float* __restrict__ deg,
                                            const float* __restrict__ bg,
                                            float* __restrict__ outp) {
  __shared__ unsigned short dvh[NPT];
  const int tid  = threadIdx.x;
  const int lane = tid & 63;
  const int w    = tid >> 6;
  const int l15  = lane & 15;
  const int g    = lane >> 4;
  const int i0 = blockIdx.x * 16;

#pragma unroll
  for (int it = 0; it < 4; ++it) {
    const int idx = it * 256 + tid;
    const _Float16 dh = (_Float16)rsqrtf(deg[idx]);
    dvh[idx] = __builtin_bit_cast(unsigned short, dh);
  }
  __syncthreads();

  f32x4 acc[2] = {f32x4{0.f, 0.f, 0.f, 0.f}, f32x4{0.f, 0.f, 0.f, 0.f}};
#pragma unroll 2
  for (int ch = 0; ch < 32; ++ch) {
    const int kofs = ch * 32 + g * 8;
    const f32x4 av0 = *(const f32x4*)&adj[(i0 + l15) * NPT + kofs];
    const f32x4 av1 = *(const f32x4*)&adj[(i0 + l15) * NPT + kofs + 4];
    const half2v* dq = (const half2v*)(dvh + kofs);
    u32x4 bu;
    bu[0] = __builtin_bit_cast(unsigned int,
        half2v(__builtin_bit_cast(half2v, pkrtz(av0[0], av0[1])) * dq[0]));
    bu[1] = __builtin_bit_cast(unsigned int,
        half2v(__builtin_bit_cast(half2v, pkrtz(av0[2], av0[3])) * dq[1]));
    bu[2] = __builtin_bit_cast(unsigned int,
        half2v(__builtin_bit_cast(half2v, pkrtz(av1[0], av1[1])) * dq[2]));
    bu[3] = __builtin_bit_cast(unsigned int,
        half2v(__builtin_bit_cast(half2v, pkrtz(av1[2], av1[3])) * dq[3]));
    const half8 bf = __builtin_bit_cast(half8, bu);
#pragma unroll
    for (int tt = 0; tt < 2; ++tt) {
      const int trow = w * 32 + tt * 16 + l15;
      const half8 af = *(const half8*)(xwghT + trow * NPT + kofs);
      acc[tt] = __builtin_amdgcn_mfma_f32_16x16x32_f16(af, bf, acc[tt], 0, 0, 0);
    }
  }
  const float di = rsqrtf(deg[i0 + l15]);
#pragma unroll
  for (int tt = 0; tt < 2; ++tt) {
    const int t0 = w * 32 + tt * 16;
    const f32x4 bgv = *(const f32x4*)&bg[t0 + g * 4];
    f32x4 o;
#pragma unroll
    for (int r = 0; r < 4; ++r) {
      const float v = acc[tt][r] * di + bgv[r];
      o[r] = v > 0.f ? v : 0.2f * v;
    }
    *(f32x4*)&outp[(i0 + l15) * D + t0 + g * 4] = o;
  }
}

extern "C" void kernel_launch(void* const* d_in, const int* in_sizes, int n_in,
                              void* d_out, int out_size, void* d_ws, size_t ws_size,
                              hipStream_t stream) {
  const float* x  = (const float*)d_in[0];
  const float* W1 = (const float*)d_in[1];
  const float* b1 = (const float*)d_in[2];
  const float* W2 = (const float*)d_in[3];
  const float* b2 = (const float*)d_in[4];
  const float* Wg = (const float*)d_in[5];
  const float* bg = (const float*)d_in[6];

  float* outp = (float*)d_out;                  // [1024*128]
  float* adj  = outp + NPT * D;                 // [1024*1024]
  unsigned char* ws = (unsigned char*)d_ws;
  float* deg            = (float*)ws;                               // 4KB @0
  unsigned short* xsw   = (unsigned short*)(ws + 4096);             // 256KB
  unsigned short* w1p   = (unsigned short*)(ws + 4096 + 262144);    // 32KB
  unsigned short* xwghT = (unsigned short*)(ws + 4096 + 262144 + 32768);  // 256KB

  k_prep<<<NPT, 128, 0, stream>>>(x, W1, Wg, deg, xsw, w1p, xwghT);
  k_adj<<<dim3(256, 2), 256, 0, stream>>>(xsw, w1p, b1, W2, b2, adj, deg);
  k_d1<<<64, 256, 0, stream>>>(adj, xwghT, deg, bg, outp);
}

// Round 17
// 45.536 us; speedup vs baseline: 1.4329x; 1.4329x over previous
//
#include <hip/hip_runtime.h>
#include <hip/hip_bf16.h>
#include <math.h>

typedef __attribute__((ext_vector_type(8))) _Float16 half8;
typedef __attribute__((ext_vector_type(2))) _Float16 half2v;
typedef __attribute__((ext_vector_type(4))) float f32x4;
typedef __attribute__((ext_vector_type(4))) unsigned int u32x4;

#define NPT 1024
#define D   128

__device__ __forceinline__ unsigned int absdiff_pk(unsigned int a, unsigned int b) {
  half2v d = __builtin_bit_cast(half2v, a) - __builtin_bit_cast(half2v, b);
  return __builtin_bit_cast(unsigned int, d) & 0x7FFF7FFFu;
}
__device__ __forceinline__ unsigned int pk_max(unsigned int a, unsigned int b) {
  unsigned int r;
  asm("v_pk_max_f16 %0, %1, %2" : "=v"(r) : "v"(a), "v"(b));
  return r;
}
__device__ __forceinline__ unsigned int pkrtz(float lo, float hi) {
  return __builtin_bit_cast(unsigned int, __builtin_amdgcn_cvt_pkrtz(lo, hi));
}
__device__ __forceinline__ float fdot2(unsigned int a, unsigned int b, float c) {
  return __builtin_amdgcn_fdot2(__builtin_bit_cast(half2v, a),
                                __builtin_bit_cast(half2v, b), c, false);
}

// ---------------- kernel 1: prep ----------------
// xsw: swizzled f16 x: row i base i*256B, elem k at ((2k)^((i&7)<<4))
// w1p: fragment-ordered f16 W1: w1p[((k>>3)*128+hid)*8 + (k&7)] = W1[k][hid]
// xwghT: f16 [128 t][1024 i] transpose of x@Wg
__global__ __launch_bounds__(128) void k_prep(const float* __restrict__ x,
                                              const float* __restrict__ W1,
                                              const float* __restrict__ Wg,
                                              unsigned short* __restrict__ xsw,
                                              unsigned short* __restrict__ w1p,
                                              unsigned short* __restrict__ xwghT) {
  __shared__ float xi[D];
  const int i = blockIdx.x;
  const int t = threadIdx.x;
  const float xv = x[i * D + t];
  xi[t] = xv;
  const _Float16 hv = (_Float16)xv;
  const int byte = i * 256 + ((2 * t) ^ ((i & 7) << 4));
  *(unsigned short*)((unsigned char*)xsw + byte) =
      __builtin_bit_cast(unsigned short, hv);
  if (i < 128) {  // t = k, i = hid
    const _Float16 wv = (_Float16)W1[t * 128 + i];
    w1p[((t >> 3) * 128 + i) * 8 + (t & 7)] = __builtin_bit_cast(unsigned short, wv);
  }
  __syncthreads();
  float a0 = 0.f, a1 = 0.f, a2 = 0.f, a3 = 0.f;
#pragma unroll 8
  for (int k = 0; k < D; k += 4) {
    a0 += xi[k + 0] * Wg[(k + 0) * D + t];
    a1 += xi[k + 1] * Wg[(k + 1) * D + t];
    a2 += xi[k + 2] * Wg[(k + 2) * D + t];
    a3 += xi[k + 3] * Wg[(k + 3) * D + t];
  }
  const _Float16 av = (_Float16)((a0 + a1) + (a2 + a3));
  xwghT[t * NPT + i] = __builtin_bit_cast(unsigned short, av);
}

// ---------------- kernel 2: adjacency, triangular pair-row (0.508x work) ----
// grid (128,4) x 256 thr. Wave = pair-rows (i, 1023-i), upper-triangle segments
// concatenated into 65 groups, chunk c covers u in [16c, 16c+16|17).
// jr addresses depend only on column group; row switch reloads xiu only.
// Engine = proven 61.3us core: W1 in 128 regs, setprio MFMA, LDS-deferred sigmoid.
__global__ __launch_bounds__(256, 2) void k_adj(const unsigned short* __restrict__ xsw,
                                                const unsigned short* __restrict__ w1p,
                                                const float* __restrict__ b1,
                                                const float* __restrict__ W2,
                                                const float* __restrict__ b2,
                                                float* __restrict__ adj) {
  __shared__ float sbuf[4][272];
  const int tid  = threadIdx.x;
  const int lane = tid & 63;
  const int w    = tid >> 6;   // 0..3
  const int l15  = lane & 15;
  const int g    = lane >> 4;  // 0..3
  const int i   = blockIdx.x * 4 + w;   // 0..511
  const int c   = blockIdx.y;           // 0..3
  const int i2  = 1023 - i;
  const int a   = i >> 4;
  const int n_i = 64 - a;                // groups in row i's segment
  const int ustart = c * 16;
  const int uend   = (c == 3) ? 65 : (ustart + 16);
  const int len    = uend - ustart;      // 16 or 17
  const int nvals  = len * 16;
  const int asc    = (blockIdx.x & 1) == 0;  // convoy stagger

  // W1 -> regs: A[m=hid][k], hid = ht*16+l15, k = ks*32+g*8+e
  half8 w1f[4][8];
#pragma unroll
  for (int ks = 0; ks < 4; ++ks)
#pragma unroll
    for (int ht = 0; ht < 8; ++ht)
      w1f[ks][ht] = *(const half8*)(w1p + ((ks * 4 + g) * 128 + ht * 16 + l15) * 8);

  // relu(a+b1)*w2 = max(a,-b1)*w2 + b1*w2 : c0 = sum b1*w2
  unsigned int nb1pk[8][2], w2pk[8][2];
  float c0 = 0.f;
#pragma unroll
  for (int ht = 0; ht < 8; ++ht) {
    const f32x4 bv = *(const f32x4*)&b1[ht * 16 + g * 4];
    const f32x4 wv = *(const f32x4*)&W2[ht * 16 + g * 4];
    c0 += bv[0] * wv[0] + bv[1] * wv[1] + bv[2] * wv[2] + bv[3] * wv[3];
    nb1pk[ht][0] = pkrtz(-bv[0], -bv[1]);
    nb1pk[ht][1] = pkrtz(-bv[2], -bv[3]);
    w2pk[ht][0] = pkrtz(wv[0], wv[1]);
    w2pk[ht][1] = pkrtz(wv[2], wv[3]);
  }
  c0 += __shfl_xor(c0, 16);
  c0 += __shfl_xor(c0, 32);
  const float B2 = b2[0] + c0;

  const unsigned char* xsb = (const unsigned char*)xsw;
  const unsigned char* jlane = xsb + l15 * 256;  // per-lane column-row base
  const int sxJ = (l15 & 7) << 4;
  const int kb0 = (0 * 64 + g * 16) ^ sxJ;
  const int kb1 = (1 * 64 + g * 16) ^ sxJ;
  const int kb2 = (2 * 64 + g * 16) ^ sxJ;
  const int kb3 = (3 * 64 + g * 16) ^ sxJ;

  float* sbw = sbuf[w];
  u32x4 xiu[4];
  int row_cur = -1;

  // initial jr load for first group
  u32x4 jr0, jr1, jr2, jr3;
  {
    const int u0 = asc ? ustart : (uend - 1);
    const int grp0 = (u0 < n_i) ? (a + u0) : (u0 - 1);
    const unsigned char* cur = jlane + grp0 * 4096;
    jr0 = *(const u32x4*)(cur + kb0);
    jr1 = *(const u32x4*)(cur + kb1);
    jr2 = *(const u32x4*)(cur + kb2);
    jr3 = *(const u32x4*)(cur + kb3);
  }

#pragma unroll 1
  for (int t = 0; t < len; ++t) {
    const int u = asc ? (ustart + t) : (uend - 1 - t);
    const int row = (u < n_i) ? i : i2;
    if (row != row_cur) {  // wave-uniform; at most once per chunk (+ first iter)
      row_cur = row;
      const unsigned char* xrow = xsb + row * 256;
      const int sxI = (row & 7) << 4;
#pragma unroll
      for (int ks = 0; ks < 4; ++ks)
        xiu[ks] = *(const u32x4*)(xrow + ((ks * 64 + g * 16) ^ sxI));
    }
    // next group's column base (prefetch target; clamped at tail)
    const int tn = (t + 1 < len) ? (t + 1) : t;
    const int un = asc ? (ustart + tn) : (uend - 1 - tn);
    const int grpn = (un < n_i) ? (a + un) : (un - 1);
    const unsigned char* nrow = jlane + grpn * 4096;

    f32x4 acc[8];
#pragma unroll
    for (int ht = 0; ht < 8; ++ht) acc[ht] = f32x4{0.f, 0.f, 0.f, 0.f};

    __builtin_amdgcn_s_setprio(1);
    {
      u32x4 afu;
#pragma unroll
      for (int p4 = 0; p4 < 4; ++p4) afu[p4] = absdiff_pk(jr0[p4], xiu[0][p4]);
      jr0 = *(const u32x4*)(nrow + kb0);
      const half8 af = __builtin_bit_cast(half8, afu);
#pragma unroll
      for (int ht = 0; ht < 8; ++ht)
        acc[ht] = __builtin_amdgcn_mfma_f32_16x16x32_f16(w1f[0][ht], af, acc[ht], 0, 0, 0);
    }
    {
      u32x4 afu;
#pragma unroll
      for (int p4 = 0; p4 < 4; ++p4) afu[p4] = absdiff_pk(jr1[p4], xiu[1][p4]);
      jr1 = *(const u32x4*)(nrow + kb1);
      const half8 af = __builtin_bit_cast(half8, afu);
#pragma unroll
      for (int ht = 0; ht < 8; ++ht)
        acc[ht] = __builtin_amdgcn_mfma_f32_16x16x32_f16(w1f[1][ht], af, acc[ht], 0, 0, 0);
    }
    {
      u32x4 afu;
#pragma unroll
      for (int p4 = 0; p4 < 4; ++p4) afu[p4] = absdiff_pk(jr2[p4], xiu[2][p4]);
      jr2 = *(const u32x4*)(nrow + kb2);
      const half8 af = __builtin_bit_cast(half8, afu);
#pragma unroll
      for (int ht = 0; ht < 8; ++ht)
        acc[ht] = __builtin_amdgcn_mfma_f32_16x16x32_f16(w1f[2][ht], af, acc[ht], 0, 0, 0);
    }
    {
      u32x4 afu;
#pragma unroll
      for (int p4 = 0; p4 < 4; ++p4) afu[p4] = absdiff_pk(jr3[p4], xiu[3][p4]);
      jr3 = *(const u32x4*)(nrow + kb3);
      const half8 af = __builtin_bit_cast(half8, afu);
#pragma unroll
      for (int ht = 0; ht < 8; ++ht)
        acc[ht] = __builtin_amdgcn_mfma_f32_16x16x32_f16(w1f[3][ht], af, acc[ht], 0, 0, 0);
    }
    __builtin_amdgcn_s_setprio(0);

    // dot: pkrtz+max -> 4 parallel fdot2 chains -> cross-lane reduce
    float sA = 0.f, sB = 0.f, sC = 0.f, sD = 0.f;
#pragma unroll
    for (int ht = 0; ht < 8; ht += 2) {
      unsigned int h0a = pk_max(pkrtz(acc[ht][0], acc[ht][1]), nb1pk[ht][0]);
      unsigned int h0b = pk_max(pkrtz(acc[ht][2], acc[ht][3]), nb1pk[ht][1]);
      unsigned int h1a = pk_max(pkrtz(acc[ht + 1][0], acc[ht + 1][1]), nb1pk[ht + 1][0]);
      unsigned int h1b = pk_max(pkrtz(acc[ht + 1][2], acc[ht + 1][3]), nb1pk[ht + 1][1]);
      sA = fdot2(h0a, w2pk[ht][0], sA);
      sB = fdot2(h0b, w2pk[ht][1], sB);
      sC = fdot2(h1a, w2pk[ht + 1][0], sC);
      sD = fdot2(h1b, w2pk[ht + 1][1], sD);
    }
    float s = (sA + sB) + (sC + sD);
    s += __shfl_xor(s, 16);
    s += __shfl_xor(s, 32);
    if (lane < 16) sbw[t * 16 + l15] = s;  // defer sigmoid/store
  }

  // epilogue: all-lane sigmoid + store (per-lane row/grp decode)
#pragma unroll 1
  for (int it = 0; it < 5; ++it) {
    const int p = it * 64 + lane;
    if (p < nvals) {
      const int tt = p >> 4;
      const int u = asc ? (ustart + tt) : (uend - 1 - tt);
      const int row = (u < n_i) ? i : i2;
      const int grp = (u < n_i) ? (a + u) : (u - 1);
      const float s = sbw[p];
      const float sig = 1.f / (1.f + __expf(-(s + B2)));
      adj[row * NPT + grp * 16 + (p & 15)] = sig;
    }
  }
}

// ---------------- kernel 2b: mirror lower triangle (proven R13) ----------------
// 2016 strictly-below-diagonal 16x16 tiles (R>C): adj[R16+r][C16+c] = adj[C16+c][R16+r].
__global__ __launch_bounds__(256) void k_sym(float* __restrict__ adj) {
  __shared__ float lds[4][16][17];
  const int tid  = threadIdx.x;
  const int lane = tid & 63;
  const int w    = tid >> 6;
  const int t = blockIdx.x * 4 + w;  // 0..2015

  int R = (int)((1.0f + sqrtf(1.0f + 8.0f * (float)t)) * 0.5f);
  if (R * (R - 1) / 2 > t) --R;
  if ((R + 1) * R / 2 <= t) ++R;
  const int C = t - R * (R - 1) / 2;

  const int r16 = lane & 15;
  const int c4  = (lane >> 4) * 4;
  const f32x4 v = *(const f32x4*)&adj[(C * 16 + r16) * NPT + R * 16 + c4];
#pragma unroll
  for (int e = 0; e < 4; ++e) lds[w][c4 + e][r16] = v[e];
  f32x4 o;
#pragma unroll
  for (int e = 0; e < 4; ++e) o[e] = lds[w][r16][c4 + e];
  *(f32x4*)&adj[(R * 16 + r16) * NPT + C * 16 + c4] = o;
}

// ---------------- kernel 2c: deg = rowsum(adj) (proven R13) ----------------
__global__ __launch_bounds__(256) void k_deg(const float* __restrict__ adj,
                                             float* __restrict__ deg) {
  const int lane = threadIdx.x & 63;
  const int w    = threadIdx.x >> 6;
  const int i = blockIdx.x * 4 + w;
  const float* row = &adj[i * NPT];
  float s = 0.f;
#pragma unroll
  for (int k = 0; k < 4; ++k) {
    const f32x4 v = *(const f32x4*)&row[(k * 64 + lane) * 4];
    s += (v[0] + v[1]) + (v[2] + v[3]);
  }
#pragma unroll
  for (int m = 1; m < 64; m <<= 1) s += __shfl_xor(s, m);
  if (lane == 0) deg[i] = s;
}

// ---------------- kernel 3: fused d1 (R10 form: (64,4)x128, no atomics) ----
// out[i][t] = leaky( dinv_i * sum_j xwghT[t][j]*(adj[i][j]*dinv_j) + bg[t] )
__global__ __launch_bounds__(128) void k_d1(const float* __restrict__ adj,
                                            const unsigned short* __restrict__ xwghT,
                                            const float* __restrict__ deg,
                                            const float* __restrict__ bg,
                                            float* __restrict__ outp) {
  __shared__ unsigned short dvh[NPT];
  const int tid  = threadIdx.x;
  const int lane = tid & 63;
  const int w    = tid >> 6;
  const int l15  = lane & 15;
  const int g    = lane >> 4;
  const int i0 = blockIdx.x * 16;
  const int t0 = (blockIdx.y * 2 + w) * 16;

#pragma unroll
  for (int it = 0; it < 8; ++it) {
    const int idx = it * 128 + tid;
    const _Float16 dh = (_Float16)rsqrtf(deg[idx]);
    dvh[idx] = __builtin_bit_cast(unsigned short, dh);
  }
  __syncthreads();

  f32x4 acc{0.f, 0.f, 0.f, 0.f};
#pragma unroll 2
  for (int ch = 0; ch < 32; ++ch) {
    const int kofs = ch * 32 + g * 8;
    const half8 af = *(const half8*)(xwghT + (t0 + l15) * NPT + kofs);
    const f32x4 av0 = *(const f32x4*)&adj[(i0 + l15) * NPT + kofs];
    const f32x4 av1 = *(const f32x4*)&adj[(i0 + l15) * NPT + kofs + 4];
    const half2v* dq = (const half2v*)(dvh + kofs);
    u32x4 bu;
    bu[0] = __builtin_bit_cast(unsigned int,
        half2v(__builtin_bit_cast(half2v, pkrtz(av0[0], av0[1])) * dq[0]));
    bu[1] = __builtin_bit_cast(unsigned int,
        half2v(__builtin_bit_cast(half2v, pkrtz(av0[2], av0[3])) * dq[1]));
    bu[2] = __builtin_bit_cast(unsigned int,
        half2v(__builtin_bit_cast(half2v, pkrtz(av1[0], av1[1])) * dq[2]));
    bu[3] = __builtin_bit_cast(unsigned int,
        half2v(__builtin_bit_cast(half2v, pkrtz(av1[2], av1[3])) * dq[3]));
    acc = __builtin_amdgcn_mfma_f32_16x16x32_f16(__builtin_bit_cast(half8, af),
                                                 __builtin_bit_cast(half8, bu), acc, 0, 0, 0);
  }
  const float di = rsqrtf(deg[i0 + l15]);
  const f32x4 bgv = *(const f32x4*)&bg[t0 + g * 4];
  f32x4 o;
#pragma unroll
  for (int r = 0; r < 4; ++r) {
    const float v = acc[r] * di + bgv[r];
    o[r] = v > 0.f ? v : 0.2f * v;
  }
  *(f32x4*)&outp[(i0 + l15) * D + t0 + g * 4] = o;
}

extern "C" void kernel_launch(void* const* d_in, const int* in_sizes, int n_in,
                              void* d_out, int out_size, void* d_ws, size_t ws_size,
                              hipStream_t stream) {
  const float* x  = (const float*)d_in[0];
  const float* W1 = (const float*)d_in[1];
  const float* b1 = (const float*)d_in[2];
  const float* W2 = (const float*)d_in[3];
  const float* b2 = (const float*)d_in[4];
  const float* Wg = (const float*)d_in[5];
  const float* bg = (const float*)d_in[6];

  float* outp = (float*)d_out;                  // [1024*128]
  float* adj  = outp + NPT * D;                 // [1024*1024]
  unsigned char* ws = (unsigned char*)d_ws;
  float* deg            = (float*)ws;                               // 4KB @0
  unsigned short* xsw   = (unsigned short*)(ws + 4096);             // 256KB
  unsigned short* w1p   = (unsigned short*)(ws + 4096 + 262144);    // 32KB
  unsigned short* xwghT = (unsigned short*)(ws + 4096 + 262144 + 32768);  // 256KB

  k_prep<<<NPT, 128, 0, stream>>>(x, W1, Wg, xsw, w1p, xwghT);
  k_adj<<<dim3(128, 4), 256, 0, stream>>>(xsw, w1p, b1, W2, b2, adj);
  k_sym<<<504, 256, 0, stream>>>(adj);
  k_deg<<<256, 256, 0, stream>>>(adj, deg);
  k_d1<<<dim3(64, 4), 128, 0, stream>>>(adj, xwghT, deg, bg, outp);
}

// Round 18
// 44.075 us; speedup vs baseline: 1.4804x; 1.0331x over previous
//
#include <hip/hip_runtime.h>
#include <hip/hip_bf16.h>
#include <math.h>

typedef __attribute__((ext_vector_type(8))) _Float16 half8;
typedef __attribute__((ext_vector_type(2))) _Float16 half2v;
typedef __attribute__((ext_vector_type(4))) float f32x4;
typedef __attribute__((ext_vector_type(4))) unsigned int u32x4;

#define NPT 1024
#define D   128

__device__ __forceinline__ unsigned int absdiff_pk(unsigned int a, unsigned int b) {
  half2v d = __builtin_bit_cast(half2v, a) - __builtin_bit_cast(half2v, b);
  return __builtin_bit_cast(unsigned int, d) & 0x7FFF7FFFu;
}
__device__ __forceinline__ unsigned int pk_max(unsigned int a, unsigned int b) {
  unsigned int r;
  asm("v_pk_max_f16 %0, %1, %2" : "=v"(r) : "v"(a), "v"(b));
  return r;
}
__device__ __forceinline__ unsigned int pkrtz(float lo, float hi) {
  return __builtin_bit_cast(unsigned int, __builtin_amdgcn_cvt_pkrtz(lo, hi));
}
__device__ __forceinline__ float fdot2(unsigned int a, unsigned int b, float c) {
  return __builtin_amdgcn_fdot2(__builtin_bit_cast(half2v, a),
                                __builtin_bit_cast(half2v, b), c, false);
}

// ---------------- kernel 1: prep ----------------
// xsw: swizzled f16 x: row i base i*256B, elem k at ((2k)^((i&7)<<4))
// w1p: fragment-ordered f16 W1: w1p[((k>>3)*128+hid)*8 + (k&7)] = W1[k][hid]
// xwghT: f16 [128 t][1024 i] transpose of x@Wg. Also zeroes deg (k_symdeg atomics).
__global__ __launch_bounds__(128) void k_prep(const float* __restrict__ x,
                                              const float* __restrict__ W1,
                                              const float* __restrict__ Wg,
                                              float* __restrict__ deg,
                                              unsigned short* __restrict__ xsw,
                                              unsigned short* __restrict__ w1p,
                                              unsigned short* __restrict__ xwghT) {
  __shared__ float xi[D];
  const int i = blockIdx.x;
  const int t = threadIdx.x;
  const float xv = x[i * D + t];
  xi[t] = xv;
  if (t == 0) deg[i] = 0.f;
  const _Float16 hv = (_Float16)xv;
  const int byte = i * 256 + ((2 * t) ^ ((i & 7) << 4));
  *(unsigned short*)((unsigned char*)xsw + byte) =
      __builtin_bit_cast(unsigned short, hv);
  if (i < 128) {  // t = k, i = hid
    const _Float16 wv = (_Float16)W1[t * 128 + i];
    w1p[((t >> 3) * 128 + i) * 8 + (t & 7)] = __builtin_bit_cast(unsigned short, wv);
  }
  __syncthreads();
  float a0 = 0.f, a1 = 0.f, a2 = 0.f, a3 = 0.f;
#pragma unroll 8
  for (int k = 0; k < D; k += 4) {
    a0 += xi[k + 0] * Wg[(k + 0) * D + t];
    a1 += xi[k + 1] * Wg[(k + 1) * D + t];
    a2 += xi[k + 2] * Wg[(k + 2) * D + t];
    a3 += xi[k + 3] * Wg[(k + 3) * D + t];
  }
  const _Float16 av = (_Float16)((a0 + a1) + (a2 + a3));
  xwghT[t * NPT + i] = __builtin_bit_cast(unsigned short, av);
}

// ---------------- kernel 2: adjacency, triangular pair-row (0.508x work) ----
// grid (128,4) x 256 thr. Wave = pair-rows (i, 1023-i), 65 upper-tri groups in
// 4 chunks. Per-group: MFMA + quadrant-partial dot -> ALL-lane sbuf write (no
// shfl on spine). Epilogue: 4-partial sum + sigmoid + store.
// asc=(by>>1)&1 anti-phases true co-resident blocks (b, b+256).
__global__ __launch_bounds__(256, 2) void k_adj(const unsigned short* __restrict__ xsw,
                                                const unsigned short* __restrict__ w1p,
                                                const float* __restrict__ b1,
                                                const float* __restrict__ W2,
                                                const float* __restrict__ b2,
                                                float* __restrict__ adj) {
  __shared__ float sbuf[4][17 * 68];  // [wave][t*68 + lane], stride-68 pad
  const int tid  = threadIdx.x;
  const int lane = tid & 63;
  const int w    = tid >> 6;   // 0..3
  const int l15  = lane & 15;
  const int g    = lane >> 4;  // 0..3
  const int i   = blockIdx.x * 4 + w;   // 0..511
  const int c   = blockIdx.y;           // 0..3
  const int i2  = 1023 - i;
  const int a   = i >> 4;
  const int n_i = 64 - a;                // groups in row i's segment
  const int ustart = c * 16;
  const int uend   = (c == 3) ? 65 : (ustart + 16);
  const int len    = uend - ustart;      // 16 or 17
  const int nvals  = len * 16;
  const int asc    = (blockIdx.y >> 1) & 1;  // anti-phase co-resident (b,b+256)

  // W1 -> regs: A[m=hid][k], hid = ht*16+l15, k = ks*32+g*8+e
  half8 w1f[4][8];
#pragma unroll
  for (int ks = 0; ks < 4; ++ks)
#pragma unroll
    for (int ht = 0; ht < 8; ++ht)
      w1f[ks][ht] = *(const half8*)(w1p + ((ks * 4 + g) * 128 + ht * 16 + l15) * 8);

  // relu(a+b1)*w2 = max(a,-b1)*w2 + b1*w2 : c0 = sum b1*w2
  unsigned int nb1pk[8][2], w2pk[8][2];
  float c0 = 0.f;
#pragma unroll
  for (int ht = 0; ht < 8; ++ht) {
    const f32x4 bv = *(const f32x4*)&b1[ht * 16 + g * 4];
    const f32x4 wv = *(const f32x4*)&W2[ht * 16 + g * 4];
    c0 += bv[0] * wv[0] + bv[1] * wv[1] + bv[2] * wv[2] + bv[3] * wv[3];
    nb1pk[ht][0] = pkrtz(-bv[0], -bv[1]);
    nb1pk[ht][1] = pkrtz(-bv[2], -bv[3]);
    w2pk[ht][0] = pkrtz(wv[0], wv[1]);
    w2pk[ht][1] = pkrtz(wv[2], wv[3]);
  }
  c0 += __shfl_xor(c0, 16);
  c0 += __shfl_xor(c0, 32);
  const float B2 = b2[0] + c0;

  const unsigned char* xsb = (const unsigned char*)xsw;
  const unsigned char* jlane = xsb + l15 * 256;  // per-lane column-row base
  const int sxJ = (l15 & 7) << 4;
  const int kb0 = (0 * 64 + g * 16) ^ sxJ;
  const int kb1 = (1 * 64 + g * 16) ^ sxJ;
  const int kb2 = (2 * 64 + g * 16) ^ sxJ;
  const int kb3 = (3 * 64 + g * 16) ^ sxJ;

  float* sbw = sbuf[w];
  u32x4 xiu[4];
  int row_cur = -1;

  // initial jr load for first group
  u32x4 jr0, jr1, jr2, jr3;
  {
    const int u0 = asc ? ustart : (uend - 1);
    const int grp0 = (u0 < n_i) ? (a + u0) : (u0 - 1);
    const unsigned char* cur = jlane + grp0 * 4096;
    jr0 = *(const u32x4*)(cur + kb0);
    jr1 = *(const u32x4*)(cur + kb1);
    jr2 = *(const u32x4*)(cur + kb2);
    jr3 = *(const u32x4*)(cur + kb3);
  }

#pragma unroll 1
  for (int t = 0; t < len; ++t) {
    const int u = asc ? (ustart + t) : (uend - 1 - t);
    const int row = (u < n_i) ? i : i2;
    if (row != row_cur) {  // wave-uniform; at most once per chunk (+ first iter)
      row_cur = row;
      const unsigned char* xrow = xsb + row * 256;
      const int sxI = (row & 7) << 4;
#pragma unroll
      for (int ks = 0; ks < 4; ++ks)
        xiu[ks] = *(const u32x4*)(xrow + ((ks * 64 + g * 16) ^ sxI));
    }
    // next group's column base (prefetch target; clamped at tail)
    const int tn = (t + 1 < len) ? (t + 1) : t;
    const int un = asc ? (ustart + tn) : (uend - 1 - tn);
    const int grpn = (un < n_i) ? (a + un) : (un - 1);
    const unsigned char* nrow = jlane + grpn * 4096;

    f32x4 acc[8];
#pragma unroll
    for (int ht = 0; ht < 8; ++ht) acc[ht] = f32x4{0.f, 0.f, 0.f, 0.f};

    __builtin_amdgcn_s_setprio(1);
    {
      u32x4 afu;
#pragma unroll
      for (int p4 = 0; p4 < 4; ++p4) afu[p4] = absdiff_pk(jr0[p4], xiu[0][p4]);
      jr0 = *(const u32x4*)(nrow + kb0);
      const half8 af = __builtin_bit_cast(half8, afu);
#pragma unroll
      for (int ht = 0; ht < 8; ++ht)
        acc[ht] = __builtin_amdgcn_mfma_f32_16x16x32_f16(w1f[0][ht], af, acc[ht], 0, 0, 0);
    }
    {
      u32x4 afu;
#pragma unroll
      for (int p4 = 0; p4 < 4; ++p4) afu[p4] = absdiff_pk(jr1[p4], xiu[1][p4]);
      jr1 = *(const u32x4*)(nrow + kb1);
      const half8 af = __builtin_bit_cast(half8, afu);
#pragma unroll
      for (int ht = 0; ht < 8; ++ht)
        acc[ht] = __builtin_amdgcn_mfma_f32_16x16x32_f16(w1f[1][ht], af, acc[ht], 0, 0, 0);
    }
    {
      u32x4 afu;
#pragma unroll
      for (int p4 = 0; p4 < 4; ++p4) afu[p4] = absdiff_pk(jr2[p4], xiu[2][p4]);
      jr2 = *(const u32x4*)(nrow + kb2);
      const half8 af = __builtin_bit_cast(half8, afu);
#pragma unroll
      for (int ht = 0; ht < 8; ++ht)
        acc[ht] = __builtin_amdgcn_mfma_f32_16x16x32_f16(w1f[2][ht], af, acc[ht], 0, 0, 0);
    }
    {
      u32x4 afu;
#pragma unroll
      for (int p4 = 0; p4 < 4; ++p4) afu[p4] = absdiff_pk(jr3[p4], xiu[3][p4]);
      jr3 = *(const u32x4*)(nrow + kb3);
      const half8 af = __builtin_bit_cast(half8, afu);
#pragma unroll
      for (int ht = 0; ht < 8; ++ht)
        acc[ht] = __builtin_amdgcn_mfma_f32_16x16x32_f16(w1f[3][ht], af, acc[ht], 0, 0, 0);
    }
    __builtin_amdgcn_s_setprio(0);

    // dot: pkrtz+max -> 4 parallel fdot2 chains; NO cross-lane reduce here —
    // all 64 lanes store their quadrant partial (deferred to epilogue).
    float sA = 0.f, sB = 0.f, sC = 0.f, sD = 0.f;
#pragma unroll
    for (int ht = 0; ht < 8; ht += 2) {
      unsigned int h0a = pk_max(pkrtz(acc[ht][0], acc[ht][1]), nb1pk[ht][0]);
      unsigned int h0b = pk_max(pkrtz(acc[ht][2], acc[ht][3]), nb1pk[ht][1]);
      unsigned int h1a = pk_max(pkrtz(acc[ht + 1][0], acc[ht + 1][1]), nb1pk[ht + 1][0]);
      unsigned int h1b = pk_max(pkrtz(acc[ht + 1][2], acc[ht + 1][3]), nb1pk[ht + 1][1]);
      sA = fdot2(h0a, w2pk[ht][0], sA);
      sB = fdot2(h0b, w2pk[ht][1], sB);
      sC = fdot2(h1a, w2pk[ht + 1][0], sC);
      sD = fdot2(h1b, w2pk[ht + 1][1], sD);
    }
    sbw[t * 68 + lane] = (sA + sB) + (sC + sD);
  }

  // epilogue: sum 4 quadrant partials, sigmoid, store (per-lane row/grp decode)
#pragma unroll 1
  for (int it = 0; it < 5; ++it) {
    const int p = it * 64 + lane;
    if (p < nvals) {
      const int tt = p >> 4;
      const int j = p & 15;
      const int u = asc ? (ustart + tt) : (uend - 1 - tt);
      const int row = (u < n_i) ? i : i2;
      const int grp = (u < n_i) ? (a + u) : (u - 1);
      const float s = sbw[tt * 68 + j] + sbw[tt * 68 + 16 + j] +
                      sbw[tt * 68 + 32 + j] + sbw[tt * 68 + 48 + j];
      const float sig = 1.f / (1.f + __expf(-(s + B2)));
      adj[row * NPT + grp * 16 + j] = sig;
    }
  }
}

// ---------------- kernel 2b: mirror lower triangle + deg accumulation ----
// blocks 0..503: strict-upper tile (C,R) -> mirror to (R,C); rowsum(src) feeds
// deg[C*16+r], colsum(src) (= rowsum of dst) feeds deg[R*16+r]. blocks 504..519:
// diagonal tiles, rowsum only. deg zeroed by k_prep.
__global__ __launch_bounds__(256) void k_symdeg(float* __restrict__ adj,
                                                float* __restrict__ deg) {
  __shared__ float lds[4][16][17];
  const int tid  = threadIdx.x;
  const int lane = tid & 63;
  const int w    = tid >> 6;
  const int r16 = lane & 15;
  const int c4  = (lane >> 4) * 4;

  if (blockIdx.x < 504) {
    const int t = blockIdx.x * 4 + w;  // 0..2015
    int R = (int)((1.0f + sqrtf(1.0f + 8.0f * (float)t)) * 0.5f);
    if (R * (R - 1) / 2 > t) --R;
    if ((R + 1) * R / 2 <= t) ++R;
    const int C = t - R * (R - 1) / 2;

    const f32x4 v = *(const f32x4*)&adj[(C * 16 + r16) * NPT + R * 16 + c4];
    float rs = (v[0] + v[1]) + (v[2] + v[3]);
    rs += __shfl_xor(rs, 16);
    rs += __shfl_xor(rs, 32);
    if (lane < 16) atomicAdd(&deg[C * 16 + r16], rs);
#pragma unroll
    for (int e = 0; e < 4; ++e) lds[w][c4 + e][r16] = v[e];
    f32x4 o;
#pragma unroll
    for (int e = 0; e < 4; ++e) o[e] = lds[w][r16][c4 + e];
    *(f32x4*)&adj[(R * 16 + r16) * NPT + C * 16 + c4] = o;
    float cs = (o[0] + o[1]) + (o[2] + o[3]);
    cs += __shfl_xor(cs, 16);
    cs += __shfl_xor(cs, 32);
    if (lane < 16) atomicAdd(&deg[R * 16 + r16], cs);
  } else {
    const int T = (blockIdx.x - 504) * 4 + w;  // 0..63 diagonal tiles
    const f32x4 v = *(const f32x4*)&adj[(T * 16 + r16) * NPT + T * 16 + c4];
    float rs = (v[0] + v[1]) + (v[2] + v[3]);
    rs += __shfl_xor(rs, 16);
    rs += __shfl_xor(rs, 32);
    if (lane < 16) atomicAdd(&deg[T * 16 + r16], rs);
  }
}

// ---------------- kernel 3: fused d1 (R10 form: (64,4)x128, no atomics) ----
// out[i][t] = leaky( dinv_i * sum_j xwghT[t][j]*(adj[i][j]*dinv_j) + bg[t] )
__global__ __launch_bounds__(128) void k_d1(const float* __restrict__ adj,
                                            const unsigned short* __restrict__ xwghT,
                                            const float* __restrict__ deg,
                                            const float* __restrict__ bg,
                                            float* __restrict__ outp) {
  __shared__ unsigned short dvh[NPT];
  const int tid  = threadIdx.x;
  const int lane = tid & 63;
  const int w    = tid >> 6;
  const int l15  = lane & 15;
  const int g    = lane >> 4;
  const int i0 = blockIdx.x * 16;
  const int t0 = (blockIdx.y * 2 + w) * 16;

#pragma unroll
  for (int it = 0; it < 8; ++it) {
    const int idx = it * 128 + tid;
    const _Float16 dh = (_Float16)rsqrtf(deg[idx]);
    dvh[idx] = __builtin_bit_cast(unsigned short, dh);
  }
  __syncthreads();

  f32x4 acc{0.f, 0.f, 0.f, 0.f};
#pragma unroll 2
  for (int ch = 0; ch < 32; ++ch) {
    const int kofs = ch * 32 + g * 8;
    const half8 af = *(const half8*)(xwghT + (t0 + l15) * NPT + kofs);
    const f32x4 av0 = *(const f32x4*)&adj[(i0 + l15) * NPT + kofs];
    const f32x4 av1 = *(const f32x4*)&adj[(i0 + l15) * NPT + kofs + 4];
    const half2v* dq = (const half2v*)(dvh + kofs);
    u32x4 bu;
    bu[0] = __builtin_bit_cast(unsigned int,
        half2v(__builtin_bit_cast(half2v, pkrtz(av0[0], av0[1])) * dq[0]));
    bu[1] = __builtin_bit_cast(unsigned int,
        half2v(__builtin_bit_cast(half2v, pkrtz(av0[2], av0[3])) * dq[1]));
    bu[2] = __builtin_bit_cast(unsigned int,
        half2v(__builtin_bit_cast(half2v, pkrtz(av1[0], av1[1])) * dq[2]));
    bu[3] = __builtin_bit_cast(unsigned int,
        half2v(__builtin_bit_cast(half2v, pkrtz(av1[2], av1[3])) * dq[3]));
    acc = __builtin_amdgcn_mfma_f32_16x16x32_f16(__builtin_bit_cast(half8, af),
                                                 __builtin_bit_cast(half8, bu), acc, 0, 0, 0);
  }
  const float di = rsqrtf(deg[i0 + l15]);
  const f32x4 bgv = *(const f32x4*)&bg[t0 + g * 4];
  f32x4 o;
#pragma unroll
  for (int r = 0; r < 4; ++r) {
    const float v = acc[r] * di + bgv[r];
    o[r] = v > 0.f ? v : 0.2f * v;
  }
  *(f32x4*)&outp[(i0 + l15) * D + t0 + g * 4] = o;
}

extern "C" void kernel_launch(void* const* d_in, const int* in_sizes, int n_in,
                              void* d_out, int out_size, void* d_ws, size_t ws_size,
                              hipStream_t stream) {
  const float* x  = (const float*)d_in[0];
  const float* W1 = (const float*)d_in[1];
  const float* b1 = (const float*)d_in[2];
  const float* W2 = (const float*)d_in[3];
  const float* b2 = (const float*)d_in[4];
  const float* Wg = (const float*)d_in[5];
  const float* bg = (const float*)d_in[6];

  float* outp = (float*)d_out;                  // [1024*128]
  float* adj  = outp + NPT * D;                 // [1024*1024]
  unsigned char* ws = (unsigned char*)d_ws;
  float* deg            = (float*)ws;                               // 4KB @0
  unsigned short* xsw   = (unsigned short*)(ws + 4096);             // 256KB
  unsigned short* w1p   = (unsigned short*)(ws + 4096 + 262144);    // 32KB
  unsigned short* xwghT = (unsigned short*)(ws + 4096 + 262144 + 32768);  // 256KB

  k_prep<<<NPT, 128, 0, stream>>>(x, W1, Wg, deg, xsw, w1p, xwghT);
  k_adj<<<dim3(128, 4), 256, 0, stream>>>(xsw, w1p, b1, W2, b2, adj);
  k_symdeg<<<520, 256, 0, stream>>>(adj, deg);
  k_d1<<<dim3(64, 4), 128, 0, stream>>>(adj, xwghT, deg, bg, outp);
}